// Round 1
// baseline (1235.934 us; speedup 1.0000x reference)
//
#include <hip/hip_runtime.h>

#define BATCH 32
#define SEQT 1000
#define INSZ 4
#define HID 2048
#define NOISE_STD 0.05f
#define ALPHA 0.2f

#define NTHREADS 512
#define EPT 4              // HID / NTHREADS
#define NWAVES 8           // NTHREADS / 64

__device__ __forceinline__ float fast_tanh(float x) {
    // tanh(x) = 1 - 2/(exp(2x)+1); exp->inf or 0 handled correctly (saturates to +/-1)
    float e = __expf(2.0f * x);
    return 1.0f - 2.0f * __builtin_amdgcn_rcpf(e + 1.0f);
}

__global__ __launch_bounds__(NTHREADS)
void rnn_kernel(const float* __restrict__ input,
                const float* __restrict__ noise,
                const float* __restrict__ wi_w,
                const float* __restrict__ m_w,
                const float* __restrict__ n_w,
                const float* __restrict__ wo_w,
                const float* __restrict__ wi_b,
                const float* __restrict__ m_b,
                const float* __restrict__ n_b,
                const float* __restrict__ h0_w,
                const float* __restrict__ gb,
                const float* __restrict__ sup,
                float* __restrict__ out)
{
    __shared__ float sIn[SEQT * INSZ];      // 16000 B: this block's input row
    __shared__ float red[2][NWAVES][4];     // parity-double-buffered reduction partials

    const int b   = blockIdx.x;
    const int tid = threadIdx.x;

    // stage input row (1000x4 floats) into LDS
    const float* inRow = input + (size_t)b * SEQT * INSZ;
    for (int i = tid; i < SEQT * INSZ; i += NTHREADS)
        sIn[i] = inRow[i];

    // ---- one-time proxy parameter computation for this thread's EPT hidden units
    const int hbase = tid * EPT;            // contiguous -> float4 noise loads coalesce
    float wiP[INSZ][EPT];
    float m0P[EPT], m1P[EPT], n0P[EPT], n1P[EPT], wo0P[EPT], wo1P[EPT];
    float hP[EPT], rP[EPT];

    #pragma unroll
    for (int e = 0; e < EPT; ++e) {
        const int h = hbase + e;
        float gv[8];
        #pragma unroll
        for (int g = 0; g < 8; ++g) gv[g] = gb[g * HID + h];
        const float s0 = sup[h];
        const float s1 = sup[HID + h];

        // w points at a [S=2][G=8] block: sum_s sup_s * (w[s,:] . gv)
        auto mix = [&](const float* w) -> float {
            float a0 = 0.f, a1 = 0.f;
            #pragma unroll
            for (int g = 0; g < 8; ++g) { a0 += w[g] * gv[g]; a1 += w[8 + g] * gv[g]; }
            return s0 * a0 + s1 * a1;
        };

        #pragma unroll
        for (int i = 0; i < INSZ; ++i)
            wiP[i][e] = mix(wi_w + i * 16) + wi_b[i * 2 + 0] * s0 + wi_b[i * 2 + 1] * s1;
        m0P[e]  = mix(m_w)      + m_b[0] * s0 + m_b[1] * s1;
        m1P[e]  = mix(m_w + 16) + m_b[2] * s0 + m_b[3] * s1;
        n0P[e]  = mix(n_w)      + n_b[0] * s0 + n_b[1] * s1;
        n1P[e]  = mix(n_w + 16) + n_b[2] * s0 + n_b[3] * s1;
        wo0P[e] = mix(wo_w);
        wo1P[e] = mix(wo_w + 16);
        {
            float a0 = 0.f, a1 = 0.f;
            #pragma unroll
            for (int g = 0; g < 8; ++g) { a0 += h0_w[g] * gv[g]; a1 += h0_w[8 + g] * gv[g]; }
            const float h0v = s0 * a0 + s1 * a1;
            hP[e] = h0v;
            rP[e] = fast_tanh(h0v);
        }
    }

    // initial partial dots from r_init: (n0, n1, wo0, wo1) . r
    float p0 = 0.f, p1 = 0.f, p2 = 0.f, p3 = 0.f;
    #pragma unroll
    for (int e = 0; e < EPT; ++e) {
        p0 += rP[e] * n0P[e];  p1 += rP[e] * n1P[e];
        p2 += rP[e] * wo0P[e]; p3 += rP[e] * wo1P[e];
    }

    // noise: one float4 per lane per step, coalesced; 2-deep prefetch
    const float4* nP = reinterpret_cast<const float4*>(noise + (size_t)b * SEQT * HID)
                       + (hbase >> 2);
    const int rowStride = HID / 4;          // float4 units per step
    float4 nsA = nP[0];
    float4 nsB = nP[rowStride];

    float* outRow = out + (size_t)b * SEQT * 2;
    const int wave = tid >> 6;
    const int lane = tid & 63;

    __syncthreads();                        // sIn ready

    auto do_step = [&](int t, float4& buf) {
        const float nx = buf.x, ny = buf.y, nz = buf.z, nw = buf.w;
        const int tpre = (t + 2 < SEQT) ? (t + 2) : (SEQT - 1);
        buf = nP[(size_t)tpre * rowStride];             // prefetch 2 steps ahead
        const float in0 = sIn[t * 4 + 0], in1 = sIn[t * 4 + 1],
                    in2 = sIn[t * 4 + 2], in3 = sIn[t * 4 + 3];

        // wave-level butterfly reduction of the 4 partials
        #pragma unroll
        for (int off = 32; off > 0; off >>= 1) {
            p0 += __shfl_xor(p0, off);
            p1 += __shfl_xor(p1, off);
            p2 += __shfl_xor(p2, off);
            p3 += __shfl_xor(p3, off);
        }
        const int par = t & 1;
        if (lane == 0) {
            red[par][wave][0] = p0; red[par][wave][1] = p1;
            red[par][wave][2] = p2; red[par][wave][3] = p3;
        }
        __syncthreads();                    // ONLY barrier per step (parity buffers)
        float y0 = 0.f, y1 = 0.f;
        #pragma unroll
        for (int w = 0; w < NWAVES; ++w) { y0 += red[par][w][0]; y1 += red[par][w][1]; }
        if (tid == 0 && t > 0) {            // out[t-1] = wo . r_{t-1}  (off critical path)
            float o0 = 0.f, o1 = 0.f;
            #pragma unroll
            for (int w = 0; w < NWAVES; ++w) { o0 += red[par][w][2]; o1 += red[par][w][3]; }
            float2 ov; ov.x = o0; ov.y = o1;
            *reinterpret_cast<float2*>(outRow + (t - 1) * 2) = ov;
        }

        // elementwise state update + next partials
        p0 = p1 = p2 = p3 = 0.f;
        const float nv[4] = {nx, ny, nz, nw};
        #pragma unroll
        for (int e = 0; e < EPT; ++e) {
            const float xin = wiP[0][e] * in0 + wiP[1][e] * in1
                            + wiP[2][e] * in2 + wiP[3][e] * in3;
            const float mv  = m0P[e] * y0 + m1P[e] * y1;
            float h = hP[e];
            h += NOISE_STD * nv[e] + ALPHA * (mv + xin - h);
            hP[e] = h;
            const float r = fast_tanh(h);
            rP[e] = r;
            p0 += r * n0P[e];  p1 += r * n1P[e];
            p2 += r * wo0P[e]; p3 += r * wo1P[e];
        }
    };

    for (int t = 0; t < SEQT; t += 2) {
        do_step(t,     nsA);
        do_step(t + 1, nsB);
    }

    // final output row: out[T-1] = wo . r_{T-1}
    #pragma unroll
    for (int off = 32; off > 0; off >>= 1) {
        p2 += __shfl_xor(p2, off);
        p3 += __shfl_xor(p3, off);
    }
    if (lane == 0) { red[0][wave][2] = p2; red[0][wave][3] = p3; }
    __syncthreads();
    if (tid == 0) {
        float o0 = 0.f, o1 = 0.f;
        #pragma unroll
        for (int w = 0; w < NWAVES; ++w) { o0 += red[0][w][2]; o1 += red[0][w][3]; }
        float2 ov; ov.x = o0; ov.y = o1;
        *reinterpret_cast<float2*>(outRow + (SEQT - 1) * 2) = ov;
    }
}

extern "C" void kernel_launch(void* const* d_in, const int* in_sizes, int n_in,
                              void* d_out, int out_size, void* d_ws, size_t ws_size,
                              hipStream_t stream) {
    const float* input = (const float*)d_in[0];
    const float* noise = (const float*)d_in[1];
    const float* wi_w  = (const float*)d_in[2];
    const float* m_w   = (const float*)d_in[3];
    const float* n_w   = (const float*)d_in[4];
    const float* wo_w  = (const float*)d_in[5];
    const float* wi_b  = (const float*)d_in[6];
    const float* m_b   = (const float*)d_in[7];
    const float* n_b   = (const float*)d_in[8];
    const float* h0_w  = (const float*)d_in[9];
    const float* gb    = (const float*)d_in[10];
    const float* sup   = (const float*)d_in[11];
    float* out = (float*)d_out;

    rnn_kernel<<<dim3(BATCH), dim3(NTHREADS), 0, stream>>>(
        input, noise, wi_w, m_w, n_w, wo_w, wi_b, m_b, n_b, h0_w, gb, sup, out);
}

// Round 2
// 894.999 us; speedup vs baseline: 1.3809x; 1.3809x over previous
//
#include <hip/hip_runtime.h>

#define BATCH 32
#define SEQT 1000
#define INSZ 4
#define HID 2048
#define NOISE_STD 0.05f
#define ALPHA 0.2f
#define ONE_M_ALPHA (1.0f - ALPHA)

#define NTHREADS 512
#define EPT 4              // HID / NTHREADS
#define NWAVES 8           // NTHREADS / 64
#define PF 4               // noise prefetch depth (== unroll)

// ---- DPP wave reduction (VALU pipe — NOT ds_swizzle/LDS pipe) ----
template<int CTRL>
__device__ __forceinline__ float dpp_add(float x) {
    // x + dpp_move(x); invalid source lanes contribute 0 (bound_ctrl=1)
    int s = __builtin_amdgcn_update_dpp(0, __float_as_int(x), CTRL, 0xF, 0xF, true);
    return x + __int_as_float(s);
}

__device__ __forceinline__ float wave_sum64_to_lane63(float x) {
    x = dpp_add<0x111>(x);   // row_shr:1
    x = dpp_add<0x112>(x);   // row_shr:2
    x = dpp_add<0x114>(x);   // row_shr:4
    x = dpp_add<0x118>(x);   // row_shr:8  -> lane15 of each row holds row sum
    x = dpp_add<0x142>(x);   // row_bcast:15 -> lane31 = rows0+1, lane63 = rows2+3
    x = dpp_add<0x143>(x);   // row_bcast:31 -> lane63 = total
    return x;
}

__device__ __forceinline__ float sum8_to_lane7(float x) {
    x = dpp_add<0x111>(x);
    x = dpp_add<0x112>(x);
    x = dpp_add<0x114>(x);   // lane7 = sum of lanes 0..7
    return x;
}

__device__ __forceinline__ float read_lane(float x, int l) {
    return __int_as_float(__builtin_amdgcn_readlane(__float_as_int(x), l));
}

__device__ __forceinline__ float fast_tanh(float x) {
    float e = __expf(2.0f * x);
    return 1.0f - 2.0f * __builtin_amdgcn_rcpf(e + 1.0f);
}

// LDS-only barrier: do NOT drain vmcnt (keeps noise prefetch in flight)
#define LDS_BARRIER() __asm__ volatile("s_waitcnt lgkmcnt(0)\ns_barrier" ::: "memory")

__global__ __launch_bounds__(NTHREADS)
void rnn_kernel(const float* __restrict__ input,
                const float* __restrict__ noise,
                const float* __restrict__ wi_w,
                const float* __restrict__ m_w,
                const float* __restrict__ n_w,
                const float* __restrict__ wo_w,
                const float* __restrict__ wi_b,
                const float* __restrict__ m_b,
                const float* __restrict__ n_b,
                const float* __restrict__ h0_w,
                const float* __restrict__ gb,
                const float* __restrict__ sup,
                float* __restrict__ out)
{
    __shared__ float4 sIn4[SEQT];        // 16000 B: this block's input rows
    __shared__ float4 sRed[2][NWAVES];   // parity-double-buffered per-wave partials

    const int b    = blockIdx.x;
    const int tid  = threadIdx.x;
    const int wave = tid >> 6;
    const int lane = tid & 63;

    // stage input row (1000 x float4) into LDS, coalesced
    const float4* inRow4 = reinterpret_cast<const float4*>(input + (size_t)b * SEQT * INSZ);
    for (int i = tid; i < SEQT; i += NTHREADS)
        sIn4[i] = inRow4[i];

    // ---- one-time proxy parameter computation for this thread's EPT hidden units
    const int hbase = tid * EPT;         // contiguous -> float4 noise loads coalesce
    float wiA[INSZ][EPT];                // alpha * wi
    float mA0[EPT], mA1[EPT];            // alpha * m
    float n0P[EPT], n1P[EPT], wo0P[EPT], wo1P[EPT];
    float hP[EPT];

    float p0 = 0.f, p1 = 0.f, p2 = 0.f, p3 = 0.f;  // partial dots (n0,n1,wo0,wo1).r

    #pragma unroll
    for (int e = 0; e < EPT; ++e) {
        const int h = hbase + e;
        float gv[8];
        #pragma unroll
        for (int g = 0; g < 8; ++g) gv[g] = gb[g * HID + h];
        const float s0 = sup[h];
        const float s1 = sup[HID + h];

        auto mix = [&](const float* w) -> float {
            float a0 = 0.f, a1 = 0.f;
            #pragma unroll
            for (int g = 0; g < 8; ++g) { a0 += w[g] * gv[g]; a1 += w[8 + g] * gv[g]; }
            return s0 * a0 + s1 * a1;
        };

        #pragma unroll
        for (int i = 0; i < INSZ; ++i)
            wiA[i][e] = ALPHA * (mix(wi_w + i * 16) + wi_b[i * 2 + 0] * s0 + wi_b[i * 2 + 1] * s1);
        mA0[e]  = ALPHA * (mix(m_w)      + m_b[0] * s0 + m_b[1] * s1);
        mA1[e]  = ALPHA * (mix(m_w + 16) + m_b[2] * s0 + m_b[3] * s1);
        n0P[e]  = mix(n_w)      + n_b[0] * s0 + n_b[1] * s1;
        n1P[e]  = mix(n_w + 16) + n_b[2] * s0 + n_b[3] * s1;
        wo0P[e] = mix(wo_w);
        wo1P[e] = mix(wo_w + 16);
        {
            float a0 = 0.f, a1 = 0.f;
            #pragma unroll
            for (int g = 0; g < 8; ++g) { a0 += h0_w[g] * gv[g]; a1 += h0_w[8 + g] * gv[g]; }
            const float h0v = s0 * a0 + s1 * a1;
            hP[e] = h0v;
            const float r = fast_tanh(h0v);
            p0 += r * n0P[e];  p1 += r * n1P[e];
            p2 += r * wo0P[e]; p3 += r * wo1P[e];
        }
    }

    // noise: one float4 per lane per step, coalesced; PF-deep prefetch
    const float4* nP = reinterpret_cast<const float4*>(noise + (size_t)b * SEQT * HID)
                       + (hbase >> 2);
    const int rowStride = HID / 4;       // float4 units per step
    float4 nsA = nP[0];
    float4 nsB = nP[1 * rowStride];
    float4 nsC = nP[2 * rowStride];
    float4 nsD = nP[3 * rowStride];

    float* outRow = out + (size_t)b * SEQT * 2;

    __syncthreads();                     // sIn4 ready (full barrier once, before loop)

    auto do_step = [&](int t, float4& nbuf) {
        // ---- stage 1: wave-level DPP reduce of partials from r_{t-1} (VALU pipe)
        float w0 = wave_sum64_to_lane63(p0);
        float w1 = wave_sum64_to_lane63(p1);
        float w2 = wave_sum64_to_lane63(p2);
        float w3 = wave_sum64_to_lane63(p3);
        const int par = t & 1;
        if (lane == 63) sRed[par][wave] = make_float4(w0, w1, w2, w3);

        // ---- phase A: y-independent half of the update (overlaps LDS write latency)
        const float4 nv4 = nbuf;
        const int tpre = (t + PF < SEQT) ? (t + PF) : (SEQT - 1);
        nbuf = nP[(size_t)tpre * rowStride];            // prefetch PF steps ahead
        const float4 inv = sIn4[t];                      // broadcast b128 read
        float acc[EPT];
        const float nv[4] = {nv4.x, nv4.y, nv4.z, nv4.w};
        #pragma unroll
        for (int e = 0; e < EPT; ++e) {
            float xin = wiA[0][e] * inv.x;
            xin = fmaf(wiA[1][e], inv.y, xin);
            xin = fmaf(wiA[2][e], inv.z, xin);
            xin = fmaf(wiA[3][e], inv.w, xin);
            acc[e] = fmaf(hP[e], ONE_M_ALPHA, fmaf(NOISE_STD, nv[e], xin));
        }

        // ---- barrier: LDS-only wait, global prefetch stays in flight
        LDS_BARRIER();

        // ---- stage 2: cross-wave reduce (1 b128 read + 3 DPP levels + readlane)
        const float4 pr = sRed[par][lane & 7];
        float y0 = sum8_to_lane7(pr.x);
        float y1 = sum8_to_lane7(pr.y);
        y0 = read_lane(y0, 7);
        y1 = read_lane(y1, 7);
        if (t > 0 && wave == 0) {        // out[t-1] = wo . r_{t-1}, off critical path
            float o0 = sum8_to_lane7(pr.z);
            float o1 = sum8_to_lane7(pr.w);
            const float o0v = read_lane(o0, 7);
            const float o1v = read_lane(o1, 7);
            if (lane == 0) {
                float2 ov; ov.x = o0v; ov.y = o1v;
                *reinterpret_cast<float2*>(outRow + (t - 1) * 2) = ov;
            }
        }

        // ---- phase C: finish update + next partials
        p0 = p1 = p2 = p3 = 0.f;
        #pragma unroll
        for (int e = 0; e < EPT; ++e) {
            float h = fmaf(mA1[e], y1, acc[e]);
            h = fmaf(mA0[e], y0, h);
            hP[e] = h;
            const float r = fast_tanh(h);
            p0 = fmaf(r, n0P[e], p0);  p1 = fmaf(r, n1P[e], p1);
            p2 = fmaf(r, wo0P[e], p2); p3 = fmaf(r, wo1P[e], p3);
        }
    };

    for (int t = 0; t < SEQT; t += PF) {
        do_step(t,     nsA);
        do_step(t + 1, nsB);
        do_step(t + 2, nsC);
        do_step(t + 3, nsD);
    }

    // final output row: out[T-1] = wo . r_{T-1}
    {
        float w2 = wave_sum64_to_lane63(p2);
        float w3 = wave_sum64_to_lane63(p3);
        if (lane == 63) sRed[0][wave] = make_float4(w2, w3, 0.f, 0.f);
        LDS_BARRIER();
        if (wave == 0) {
            const float4 pr = sRed[0][lane & 7];
            float o0 = sum8_to_lane7(pr.x);
            float o1 = sum8_to_lane7(pr.y);
            const float o0v = read_lane(o0, 7);
            const float o1v = read_lane(o1, 7);
            if (lane == 0) {
                float2 ov; ov.x = o0v; ov.y = o1v;
                *reinterpret_cast<float2*>(outRow + (SEQT - 1) * 2) = ov;
            }
        }
    }
}

extern "C" void kernel_launch(void* const* d_in, const int* in_sizes, int n_in,
                              void* d_out, int out_size, void* d_ws, size_t ws_size,
                              hipStream_t stream) {
    const float* input = (const float*)d_in[0];
    const float* noise = (const float*)d_in[1];
    const float* wi_w  = (const float*)d_in[2];
    const float* m_w   = (const float*)d_in[3];
    const float* n_w   = (const float*)d_in[4];
    const float* wo_w  = (const float*)d_in[5];
    const float* wi_b  = (const float*)d_in[6];
    const float* m_b   = (const float*)d_in[7];
    const float* n_b   = (const float*)d_in[8];
    const float* h0_w  = (const float*)d_in[9];
    const float* gb    = (const float*)d_in[10];
    const float* sup   = (const float*)d_in[11];
    float* out = (float*)d_out;

    rnn_kernel<<<dim3(BATCH), dim3(NTHREADS), 0, stream>>>(
        input, noise, wi_w, m_w, n_w, wo_w, wi_b, m_b, n_b, h0_w, gb, sup, out);
}